// Round 10
// baseline (370.864 us; speedup 1.0000x reference)
//
#include <hip/hip_runtime.h>
#include <hip/hip_bf16.h>
#include <math.h>

#define T_TOK 8192
#define EMB   1024
#define HID   1536
#define NE    8

typedef float  floatx4 __attribute__((ext_vector_type(4)));
typedef __bf16 bf16x8  __attribute__((ext_vector_type(8)));

// ---- workspace layout (bytes) ----
#define WS_COUNTS   0
#define WS_OFFSETS  1024
#define WS_FLAGS    2048
#define WS_TOKMAP   8192        // T*8*4
#define WS_TOKLIST  270336      // NE*T*4
#define WS_YBUF     532480      // ybuf 16384*1024*2; xbf aliases it (dead before gemm2 writes)
#define WS_W1T      34086912    // 25165824
#define WS_W2T      59252736    // 25165824
#define WS_H        84418560    // hbuf 16512 rows * 1536 * 2 (128-row pad for tail tiles)
#define WS_NEEDED   135143424

__device__ __forceinline__ float eload(const void* p, size_t idx, bool f32) {
  return f32 ? ((const float*)p)[idx] : (float)(((const __bf16*)p)[idx]);
}

// async global->LDS, 16B per lane; LDS dest = wave-uniform base + lane*16
__device__ __forceinline__ void glds16(const void* g, void* l) {
  __builtin_amdgcn_global_load_lds(
      (const __attribute__((address_space(1))) unsigned int*)g,
      (__attribute__((address_space(3))) unsigned int*)l, 16, 0, 0);
}

// ---------------- dtype sniff ----------------
__global__ __launch_bounds__(256)
void sniff_kernel(const void* p0, const void* p1, const void* p2, const void* p3,
                  const void* p4, const void* p5, const void* p6, int* flags) {
  const void* ps[7] = {p0, p1, p2, p3, p4, p5, p6};
  const int nelem[7] = {T_TOK * EMB, EMB * NE, NE, NE * EMB * HID, NE * HID, NE * HID * EMB, NE * EMB};
  int t = blockIdx.x;
  const unsigned* w = (const unsigned*)ps[t];
  int nw = nelem[t] / 2;
  if (nw > 2048) nw = 2048;
  __shared__ int s_pl, s_nz;
  if (threadIdx.x == 0) { s_pl = 0; s_nz = 0; }
  __syncthreads();
  int pl = 0, nz = 0;
  for (int i = threadIdx.x; i < nw; i += 256) {
    unsigned v = w[i];
    if (v == 0) continue;
    nz++;
    unsigned e = (v >> 23) & 0xFF;
    if (e >= 100 && e <= 150) pl++;
  }
  atomicAdd(&s_pl, pl);
  atomicAdd(&s_nz, nz);
  __syncthreads();
  if (threadIdx.x == 0) flags[t] = (2 * s_pl > s_nz) ? 1 : 0;
}

// =====================================================================
// prep_kernel: fused weight transposes + logits/top-k/x->bf16.
// blocks [0,3072): W1 [E][H]->w1t [H][E] per expert (24n x 16k tiles)
// blocks [3072,6144): W2 [H][E]->w2t [E][H] per expert (16n x 24k tiles)
// blocks [6144,8192): logits for 4 tokens each (one wave per token)
// Fusing removes a launch drain and co-schedules two memory-bound phases.
// =====================================================================
__global__ __launch_bounds__(256)
void prep_kernel(const void* __restrict__ W1, const void* __restrict__ W2,
                 __bf16* __restrict__ w1t, __bf16* __restrict__ w2t,
                 const void* __restrict__ x, const void* __restrict__ Wr,
                 const void* __restrict__ br, const int* __restrict__ kptr,
                 const int* __restrict__ flags, int* __restrict__ topk,
                 __bf16* __restrict__ xbf) {
  __shared__ __bf16 tile[64][66];       // transpose role only
  const int bid = blockIdx.x;
  const int tid = threadIdx.x;

  if (bid < 6144) {
    const void* in; __bf16* out; int K, N; bool f32; int e, nb, kb;
    if (bid < 3072) {
      in = W1; out = w1t; K = EMB; N = HID; f32 = flags[3] != 0;
      e = bid / 384; int rem = bid % 384; nb = rem % 24; kb = rem / 24;
    } else {
      in = W2; out = w2t; K = HID; N = EMB; f32 = flags[5] != 0;
      int w = bid - 3072; e = w / 384; int rem = w % 384; nb = rem % 16; kb = rem / 16;
    }
    size_t eoff = (size_t)e * (size_t)K * (size_t)N;
    const int n0 = nb * 64;
    const int k0 = kb * 64;

    if (f32) {
      const int nn = (tid & 15) * 4;
      const int kr = tid >> 4;
#pragma unroll
      for (int p = 0; p < 4; ++p) {
        const int k = kr + p * 16;
        float4 v = *(const float4*)((const float*)in + eoff + (size_t)(k0 + k) * N + n0 + nn);
        tile[k][nn + 0] = (__bf16)v.x; tile[k][nn + 1] = (__bf16)v.y;
        tile[k][nn + 2] = (__bf16)v.z; tile[k][nn + 3] = (__bf16)v.w;
      }
    } else {
      const int nn = (tid & 7) * 8;
      const int kr = tid >> 3;
#pragma unroll
      for (int p = 0; p < 2; ++p) {
        const int k = kr + p * 32;
        bf16x8 v = *(const bf16x8*)((const __bf16*)in + eoff + (size_t)(k0 + k) * N + n0 + nn);
#pragma unroll
        for (int j = 0; j < 8; ++j) tile[k][nn + j] = v[j];
      }
    }
    __syncthreads();
    const int kk = (tid & 7) * 8;
    const int nr = tid >> 3;
#pragma unroll
    for (int p = 0; p < 2; ++p) {
      const int n = nr + p * 32;
      bf16x8 o;
#pragma unroll
      for (int j = 0; j < 8; ++j) o[j] = tile[kk + j][n];
      *(bf16x8*)(out + eoff + (size_t)(n0 + n) * K + k0 + kk) = o;
    }
    return;
  }

  // ---- logits role ----
  const bool xf32  = flags[0] != 0;
  const bool wrf32 = flags[1] != 0;
  const bool brf32 = flags[2] != 0;
  const int wave = tid >> 6;
  const int lane = tid & 63;
  const int t = (bid - 6144) * 4 + wave;

  float xv[16];
  {
    size_t base = (size_t)t * EMB + lane * 16;
    if (xf32) {
      const float* g = (const float*)x + base;
#pragma unroll
      for (int c = 0; c < 4; ++c) {
        float4 v = *(const float4*)(g + c * 4);
        xv[c * 4 + 0] = v.x; xv[c * 4 + 1] = v.y; xv[c * 4 + 2] = v.z; xv[c * 4 + 3] = v.w;
      }
    } else {
      bf16x8 u = *(const bf16x8*)((const __bf16*)x + base);
      bf16x8 v = *(const bf16x8*)((const __bf16*)x + base + 8);
#pragma unroll
      for (int j = 0; j < 8; ++j) { xv[j] = (float)u[j]; xv[8 + j] = (float)v[j]; }
    }
  }
  {
    bf16x8 o0, o1;
#pragma unroll
    for (int j = 0; j < 8; ++j) { o0[j] = (__bf16)xv[j]; o1[j] = (__bf16)xv[8 + j]; }
    __bf16* xo = xbf + (size_t)t * EMB + lane * 16;
    *(bf16x8*)xo = o0;
    *(bf16x8*)(xo + 8) = o1;
  }
  float acc[NE];
#pragma unroll
  for (int e = 0; e < NE; ++e) acc[e] = 0.f;
  if (wrf32) {
#pragma unroll
    for (int j = 0; j < 16; ++j) {
      const float* wr = (const float*)Wr + (size_t)(lane * 16 + j) * NE;
#pragma unroll
      for (int e = 0; e < NE; ++e) acc[e] += xv[j] * wr[e];
    }
  } else {
#pragma unroll
    for (int j = 0; j < 16; ++j) {
      bf16x8 wr = *(const bf16x8*)((const __bf16*)Wr + (size_t)(lane * 16 + j) * NE);
#pragma unroll
      for (int e = 0; e < NE; ++e) acc[e] += xv[j] * (float)wr[e];
    }
  }
#pragma unroll
  for (int e = 0; e < NE; ++e) {
#pragma unroll
    for (int off = 32; off > 0; off >>= 1)
      acc[e] += __shfl_xor(acc[e], off, 64);
  }
  if (lane == 0) {
    int k = kptr[0];
    if (k < 1) k = 1; if (k > NE) k = NE;
    float lg[NE];
#pragma unroll
    for (int e = 0; e < NE; ++e) lg[e] = acc[e] + eload(br, e, brf32);
    for (int s = 0; s < k; ++s) {
      int bi = 0; float bv = lg[0];
#pragma unroll
      for (int e = 1; e < NE; ++e) { if (lg[e] > bv) { bv = lg[e]; bi = e; } }
      lg[bi] = -3.0e38f;
      topk[t * 8 + s] = bi;
    }
  }
}

// =====================================================================
// bin_kernel: single block, 1024 threads. One atomic pass assigns each
// (token, slot) a within-expert position pos; tok_list[e][pos] = t and
// tokmap = (e<<16)|pos. Row order within an expert is nondeterministic
// but output-invariant (each row computes the same y for its token).
// Then scan -> counts/offsets, then zero the 128-row tok_list pads
// (replaces bin1+scan+bin2+memset: 4 launches -> 1).
// =====================================================================
__global__ __launch_bounds__(1024)
void bin_kernel(const int* __restrict__ kptr, int* __restrict__ tokmap,
                int* __restrict__ tok_list, int* __restrict__ counts,
                int* __restrict__ offsets) {
  __shared__ int lcnt[NE];
  __shared__ int soff[NE + 1];
  const int tid = threadIdx.x;
  if (tid < NE) lcnt[tid] = 0;
  __syncthreads();
  int k = kptr[0];
  if (k < 1) k = 1; if (k > NE) k = NE;
  for (int t = tid; t < T_TOK; t += 1024) {
    for (int s = 0; s < k; ++s) {
      int e = tokmap[t * 8 + s] & 7;
      int pos = atomicAdd(&lcnt[e], 1);
      tok_list[e * T_TOK + pos] = t;
      tokmap[t * 8 + s] = (e << 16) | pos;
    }
  }
  __syncthreads();
  if (tid == 0) {
    int s = 0;
    for (int e = 0; e < NE; ++e) { soff[e] = s; s += lcnt[e]; }
    soff[NE] = s;
  }
  __syncthreads();
  if (tid < NE) counts[tid] = lcnt[tid];
  if (tid <= NE) offsets[tid] = soff[tid];
  // zero tok_list pads so gemm1 tail tiles read token 0 (masked at write)
  for (int e = 0; e < NE; ++e) {
    const int c = lcnt[e];
    const int end = (c + 127) & ~127;
    for (int i = c + tid; i < end; i += 1024) tok_list[e * T_TOK + i] = 0;
  }
}

// =====================================================================
// m97-structure grouped GEMM, BK=64 (unchanged from round 8; 73us/31%):
// 128x128 tile, 256 threads = 4 waves, 32KB LDS, 2 barriers/K-step.
// Swizzle: LDS[R][c] holds global chunk c^(R&7); reads use (s*4+fc)^(R&7).
// =====================================================================

// ---------------- GEMM1: h = gelu(x_gather @ W1[e] + b1[e]) ----------------
__global__ __launch_bounds__(256, 4)
void gemm1_kernel(const __bf16* __restrict__ xbf, const __bf16* __restrict__ w1t,
                  const void* __restrict__ b1, const int* __restrict__ counts,
                  const int* __restrict__ offsets, const int* __restrict__ tok_list,
                  const int* __restrict__ flags, __bf16* __restrict__ hbuf) {
  const int flat = blockIdx.x;
  const int e   = flat & 7;              // expert -> XCD pin
  const int idx = flat >> 3;             // 0..191
  const int g   = idx / 12;              // 0..15 (mT stride group)
  const int nT  = idx % 12;              // 0..11
  const int cnt = counts[e];
  const bool b1f32 = flags[4] != 0;

  __shared__ __align__(16) __bf16 As[128 * 64];
  __shared__ __align__(16) __bf16 Bs[128 * 64];

  const int wave = threadIdx.x >> 6;
  const int lane = threadIdx.x & 63;
  const int lrow = lane >> 3;            // 0..7
  const int cgs  = (lane & 7) ^ lrow;    // swizzled source chunk

  int Rst[4];
#pragma unroll
  for (int q = 0; q < 4; ++q) Rst[q] = (q * 4 + wave) * 8 + lrow;

  const __bf16* pB[4];
#pragma unroll
  for (int q = 0; q < 4; ++q)
    pB[q] = w1t + ((size_t)e * HID + nT * 128 + Rst[q]) * EMB + cgs * 8;

  const int wm = (wave & 1) * 64;
  const int wn = (wave >> 1) * 64;
  const int fr = lane & 15;
  const int fc = lane >> 4;
  int aOff0[4], aOff1[4], bOff0[4], bOff1[4];
#pragma unroll
  for (int i = 0; i < 4; ++i) {
    int R = wm + i * 16 + fr;
    aOff0[i] = R * 128 + (((fc)     ^ (R & 7)) << 4);
    aOff1[i] = R * 128 + (((fc + 4) ^ (R & 7)) << 4);
  }
#pragma unroll
  for (int j = 0; j < 4; ++j) {
    int R = wn + j * 16 + fr;
    bOff0[j] = R * 128 + (((fc)     ^ (R & 7)) << 4);
    bOff1[j] = R * 128 + (((fc + 4) ^ (R & 7)) << 4);
  }

  const int colBase = nT * 128 + wn + fr;
  float bv[4];
#pragma unroll
  for (int j = 0; j < 4; ++j) bv[j] = eload(b1, (size_t)e * HID + colBase + j * 16, b1f32);

  for (int mT = g; mT * 128 < cnt; mT += 16) {
    const __bf16* pA[4];
#pragma unroll
    for (int q = 0; q < 4; ++q) {
      const int tok = tok_list[e * T_TOK + mT * 128 + Rst[q]];  // pad entries = 0
      pA[q] = xbf + (size_t)tok * EMB + cgs * 8;
    }

    floatx4 acc[4][4];
#pragma unroll
    for (int i = 0; i < 4; ++i)
#pragma unroll
      for (int j = 0; j < 4; ++j) acc[i][j] = (floatx4){0.f, 0.f, 0.f, 0.f};

    for (int kb = 0; kb < EMB / 64; ++kb) {
      __syncthreads();
#pragma unroll
      for (int q = 0; q < 4; ++q) glds16(pA[q] + (size_t)kb * 64, As + (q * 4 + wave) * 512);
#pragma unroll
      for (int q = 0; q < 4; ++q) glds16(pB[q] + (size_t)kb * 64, Bs + (q * 4 + wave) * 512);
      __syncthreads();
      bf16x8 af[4], bfr[4];
#pragma unroll
      for (int i = 0; i < 4; ++i) af[i]  = *(const bf16x8*)((const char*)As + aOff0[i]);
#pragma unroll
      for (int j = 0; j < 4; ++j) bfr[j] = *(const bf16x8*)((const char*)Bs + bOff0[j]);
#pragma unroll
      for (int i = 0; i < 4; ++i)
#pragma unroll
        for (int j = 0; j < 4; ++j)
          acc[i][j] = __builtin_amdgcn_mfma_f32_16x16x32_bf16(af[i], bfr[j], acc[i][j], 0, 0, 0);
#pragma unroll
      for (int i = 0; i < 4; ++i) af[i]  = *(const bf16x8*)((const char*)As + aOff1[i]);
#pragma unroll
      for (int j = 0; j < 4; ++j) bfr[j] = *(const bf16x8*)((const char*)Bs + bOff1[j]);
#pragma unroll
      for (int i = 0; i < 4; ++i)
#pragma unroll
        for (int j = 0; j < 4; ++j)
          acc[i][j] = __builtin_amdgcn_mfma_f32_16x16x32_bf16(af[i], bfr[j], acc[i][j], 0, 0, 0);
    }

    const int hBase = offsets[e] + mT * 128;
#pragma unroll
    for (int i = 0; i < 4; ++i) {
      const int rowLoc = wm + i * 16 + fc * 4;
#pragma unroll
      for (int r = 0; r < 4; ++r) {
        const int row = rowLoc + r;
        if (mT * 128 + row < cnt) {
          __bf16* hp = hbuf + (size_t)(hBase + row) * HID + colBase;
#pragma unroll
          for (int j = 0; j < 4; ++j) {
            float v = acc[i][j][r] + bv[j];
            float gl = 0.5f * v * (1.0f + erff(v * 0.70710678118654752f));
            hp[j * 16] = (__bf16)gl;
          }
        }
      }
    }
  }
}

// ---------------- GEMM2: ybuf[row] = h @ W2[e] + b2[e] ----------------
__global__ __launch_bounds__(256, 4)
void gemm2_kernel(const __bf16* __restrict__ hbuf, const __bf16* __restrict__ w2t,
                  const void* __restrict__ b2, const int* __restrict__ counts,
                  const int* __restrict__ offsets, const int* __restrict__ flags,
                  __bf16* __restrict__ ybuf) {
  const int flat = blockIdx.x;
  const int e   = flat & 7;
  const int idx = flat >> 3;             // 0..127
  const int g   = idx >> 3;              // 0..15
  const int nT  = idx & 7;               // 0..7
  const int cnt = counts[e];
  const bool b2f32 = flags[6] != 0;

  __shared__ __align__(16) __bf16 As[128 * 64];
  __shared__ __align__(16) __bf16 Bs[128 * 64];

  const int wave = threadIdx.x >> 6;
  const int lane = threadIdx.x & 63;
  const int lrow = lane >> 3;
  const int cgs  = (lane & 7) ^ lrow;

  int Rst[4];
#pragma unroll
  for (int q = 0; q < 4; ++q) Rst[q] = (q * 4 + wave) * 8 + lrow;

  const __bf16* pB[4];
#pragma unroll
  for (int q = 0; q < 4; ++q)
    pB[q] = w2t + ((size_t)e * EMB + nT * 128 + Rst[q]) * HID + cgs * 8;

  const int wm = (wave & 1) * 64;
  const int wn = (wave >> 1) * 64;
  const int fr = lane & 15;
  const int fc = lane >> 4;
  int aOff0[4], aOff1[4], bOff0[4], bOff1[4];
#pragma unroll
  for (int i = 0; i < 4; ++i) {
    int R = wm + i * 16 + fr;
    aOff0[i] = R * 128 + (((fc)     ^ (R & 7)) << 4);
    aOff1[i] = R * 128 + (((fc + 4) ^ (R & 7)) << 4);
  }
#pragma unroll
  for (int j = 0; j < 4; ++j) {
    int R = wn + j * 16 + fr;
    bOff0[j] = R * 128 + (((fc)     ^ (R & 7)) << 4);
    bOff1[j] = R * 128 + (((fc + 4) ^ (R & 7)) << 4);
  }

  const int colBase = nT * 128 + wn + fr;
  float bv[4];
#pragma unroll
  for (int j = 0; j < 4; ++j) bv[j] = eload(b2, (size_t)e * EMB + colBase + j * 16, b2f32);

  for (int mT = g; mT * 128 < cnt; mT += 16) {
    const int rowBase = offsets[e] + mT * 128;
    const __bf16* pA[4];
#pragma unroll
    for (int q = 0; q < 4; ++q)
      pA[q] = hbuf + (size_t)(rowBase + Rst[q]) * HID + cgs * 8;

    floatx4 acc[4][4];
#pragma unroll
    for (int i = 0; i < 4; ++i)
#pragma unroll
      for (int j = 0; j < 4; ++j) acc[i][j] = (floatx4){0.f, 0.f, 0.f, 0.f};

    for (int kb = 0; kb < HID / 64; ++kb) {
      __syncthreads();
#pragma unroll
      for (int q = 0; q < 4; ++q) glds16(pA[q] + (size_t)kb * 64, As + (q * 4 + wave) * 512);
#pragma unroll
      for (int q = 0; q < 4; ++q) glds16(pB[q] + (size_t)kb * 64, Bs + (q * 4 + wave) * 512);
      __syncthreads();
      bf16x8 af[4], bfr[4];
#pragma unroll
      for (int i = 0; i < 4; ++i) af[i]  = *(const bf16x8*)((const char*)As + aOff0[i]);
#pragma unroll
      for (int j = 0; j < 4; ++j) bfr[j] = *(const bf16x8*)((const char*)Bs + bOff0[j]);
#pragma unroll
      for (int i = 0; i < 4; ++i)
#pragma unroll
        for (int j = 0; j < 4; ++j)
          acc[i][j] = __builtin_amdgcn_mfma_f32_16x16x32_bf16(af[i], bfr[j], acc[i][j], 0, 0, 0);
#pragma unroll
      for (int i = 0; i < 4; ++i) af[i]  = *(const bf16x8*)((const char*)As + aOff1[i]);
#pragma unroll
      for (int j = 0; j < 4; ++j) bfr[j] = *(const bf16x8*)((const char*)Bs + bOff1[j]);
#pragma unroll
      for (int i = 0; i < 4; ++i)
#pragma unroll
        for (int j = 0; j < 4; ++j)
          acc[i][j] = __builtin_amdgcn_mfma_f32_16x16x32_bf16(af[i], bfr[j], acc[i][j], 0, 0, 0);
    }

#pragma unroll
    for (int i = 0; i < 4; ++i) {
      const int rowLoc = wm + i * 16 + fc * 4;
#pragma unroll
      for (int r = 0; r < 4; ++r) {
        const int row = rowLoc + r;
        if (mT * 128 + row < cnt) {
          __bf16* yp = ybuf + (size_t)(rowBase + row) * EMB + colBase;
#pragma unroll
          for (int j = 0; j < 4; ++j)
            yp[j * 16] = (__bf16)(acc[i][j][r] + bv[j]);
        }
      }
    }
  }
}

// ---------------- combine: out[t] = (sum_s ybuf[offsets[e]+pos]) / k ----------------
__global__ __launch_bounds__(256)
void combine_kernel(const __bf16* __restrict__ ybuf, const int* __restrict__ tokmap,
                    const int* __restrict__ offsets, const int* __restrict__ kptr,
                    const int* __restrict__ flags, void* __restrict__ out) {
  const bool f32 = flags[0] != 0;
  const int wave = threadIdx.x >> 6;
  const int lane = threadIdx.x & 63;
  const int t = blockIdx.x * 4 + wave;
  int k = kptr[0];
  if (k < 1) k = 1; if (k > NE) k = NE;
  const float invk = 1.0f / (float)k;
  int rows[NE];
  for (int s = 0; s < k; ++s) {
    int m = tokmap[t * 8 + s];
    rows[s] = offsets[(m >> 16) & 7] + (m & 0xFFFF);
  }
#pragma unroll
  for (int c = 0; c < 2; ++c) {
    const int i = c * 512 + lane * 8;
    float a[8];
#pragma unroll
    for (int j = 0; j < 8; ++j) a[j] = 0.f;
    for (int s = 0; s < k; ++s) {
      bf16x8 y = *(const bf16x8*)(ybuf + (size_t)rows[s] * EMB + i);
#pragma unroll
      for (int j = 0; j < 8; ++j) a[j] += (float)y[j];
    }
    if (f32) {
      float* op = (float*)out + (size_t)t * EMB + i;
      float4 u = {a[0] * invk, a[1] * invk, a[2] * invk, a[3] * invk};
      float4 v = {a[4] * invk, a[5] * invk, a[6] * invk, a[7] * invk};
      *(float4*)op = u;
      *(float4*)(op + 4) = v;
    } else {
      bf16x8 o;
#pragma unroll
      for (int j = 0; j < 8; ++j) o[j] = (__bf16)(a[j] * invk);
      *(bf16x8*)((__bf16*)out + (size_t)t * EMB + i) = o;
    }
  }
}

extern "C" void kernel_launch(void* const* d_in, const int* in_sizes, int n_in,
                              void* d_out, int out_size, void* d_ws, size_t ws_size,
                              hipStream_t stream) {
  (void)in_sizes; (void)n_in; (void)out_size;
  if (ws_size < (size_t)WS_NEEDED) return;

  const void* x  = d_in[0];
  const void* Wr = d_in[1];
  const void* br = d_in[2];
  const void* W1 = d_in[3];
  const void* b1 = d_in[4];
  const void* W2 = d_in[5];
  const void* b2 = d_in[6];
  const int* kptr = (const int*)d_in[7];

  char* ws = (char*)d_ws;
  int*    counts   = (int*)(ws + WS_COUNTS);
  int*    offsets  = (int*)(ws + WS_OFFSETS);
  int*    flags    = (int*)(ws + WS_FLAGS);
  int*    tokmap   = (int*)(ws + WS_TOKMAP);
  int*    tok_list = (int*)(ws + WS_TOKLIST);
  __bf16* ybuf     = (__bf16*)(ws + WS_YBUF);
  __bf16* xbf      = (__bf16*)(ws + WS_YBUF);   // aliases ybuf; dead before gemm2 writes
  __bf16* w1t      = (__bf16*)(ws + WS_W1T);
  __bf16* w2t      = (__bf16*)(ws + WS_W2T);
  __bf16* hbuf     = (__bf16*)(ws + WS_H);

  sniff_kernel<<<dim3(7), 256, 0, stream>>>(x, Wr, br, W1, b1, W2, b2, flags);

  prep_kernel<<<dim3(6144 + T_TOK / 4), 256, 0, stream>>>(
      W1, W2, w1t, w2t, x, Wr, br, kptr, flags, tokmap, xbf);

  bin_kernel<<<dim3(1), 1024, 0, stream>>>(kptr, tokmap, tok_list, counts, offsets);

  gemm1_kernel<<<dim3(8 * 16 * 12), 256, 0, stream>>>(
      xbf, w1t, b1, counts, offsets, tok_list, flags, hbuf);
  gemm2_kernel<<<dim3(8 * 16 * 8), 256, 0, stream>>>(
      hbuf, w2t, b2, counts, offsets, flags, ybuf);

  combine_kernel<<<dim3(T_TOK / 4), 256, 0, stream>>>(ybuf, tokmap, offsets, kptr, flags, d_out);
}